// Round 1
// baseline (88.894 us; speedup 1.0000x reference)
//
#include <hip/hip_runtime.h>

#define NB 32
#define NC 256
#define NH 64
#define NW 64
#define NCM 128
#define NCO 256
#define NL 128   // NH+NW

// ---------------- Kernel 1: H/W mean pooling ----------------
// grid: NB*NC blocks (one per plane), block 256 threads.
// pool layout: [b][c][l], l<64 = mean over W (xh), l>=64 = mean over H (xw)
__global__ __launch_bounds__(256) void k_pool(const float* __restrict__ x,
                                              float* __restrict__ pool) {
    int plane = blockIdx.x;                  // b*NC + c
    const float4* px = (const float4*)(x + (size_t)plane * 4096);
    int t = threadIdx.x;
    __shared__ float smem[256 * 4];

    float4 csum = make_float4(0.f, 0.f, 0.f, 0.f);
    for (int i = 0; i < 4; ++i) {
        int f = t + i * 256;                 // float4 index in plane (1024 total)
        float4 v = px[f];
        csum.x += v.x; csum.y += v.y; csum.z += v.z; csum.w += v.w;
        // row sum: row = f/16 = t/16 + 16*i, col4 = t%16 ; reduce 16-lane group
        float s = v.x + v.y + v.z + v.w;
        s += __shfl_xor(s, 1);
        s += __shfl_xor(s, 2);
        s += __shfl_xor(s, 4);
        s += __shfl_xor(s, 8);
        if ((t & 15) == 0) {
            int row = (t >> 4) + 16 * i;
            pool[(size_t)plane * NL + row] = s * 0.015625f;   // xh
        }
    }
    // csum holds cols [4*(t%16) .. +3] summed over rows {t/16 + 16*i}
    ((float4*)smem)[t] = csum;
    __syncthreads();
    if (t < 64) {
        int m = t >> 2, k = t & 3;           // column = 4m+k = t
        float acc = 0.f;
        #pragma unroll
        for (int g = 0; g < 16; ++g)
            acc += smem[(m + 16 * g) * 4 + k];
        pool[(size_t)plane * NL + 64 + t] = acc * 0.015625f;  // xw
    }
}

// ---------------- Kernel 2: y = w1 @ pool, BN, hswish ----------------
// grid: (NB, 4) — 32m-tile each; block 256 threads; thread: 4m x 4l
__global__ __launch_bounds__(256) void k_mlp1(const float* __restrict__ pool,
                                              const float* __restrict__ w1,
                                              const float* __restrict__ b1,
                                              const float* __restrict__ gam,
                                              const float* __restrict__ bet,
                                              const float* __restrict__ mu,
                                              const float* __restrict__ var,
                                              float* __restrict__ a) {
    int b = blockIdx.x, m0 = blockIdx.y * 32;
    int t = threadIdx.x;
    __shared__ float w1t[32][32];   // [c][m]
    __shared__ float pt[32][NL];    // [c][l]
    const float* poolb = pool + (size_t)b * NC * NL;
    int ml0 = (t & 7) * 4;
    int ll0 = (t >> 3) * 4;
    float acc[4][4] = {};

    for (int cc = 0; cc < NC; cc += 32) {
        {   // stage w1 transposed: mi = t%32 (m), c0 = (t/32)*4
            int mi = t & 31, c0 = (t >> 5) * 4;
            float4 wv = *(const float4*)(w1 + (size_t)(m0 + mi) * NC + cc + c0);
            w1t[c0 + 0][mi] = wv.x; w1t[c0 + 1][mi] = wv.y;
            w1t[c0 + 2][mi] = wv.z; w1t[c0 + 3][mi] = wv.w;
        }
        #pragma unroll
        for (int i = 0; i < 4; ++i) {        // stage pool tile 32x128
            int f = t + i * 256;
            int ci = f >> 5, l4 = f & 31;
            *(float4*)&pt[ci][l4 * 4] =
                *(const float4*)(poolb + (size_t)(cc + ci) * NL + l4 * 4);
        }
        __syncthreads();
        #pragma unroll
        for (int cj = 0; cj < 32; ++cj) {
            float4 wv = *(const float4*)&w1t[cj][ml0];
            float4 pv = *(const float4*)&pt[cj][ll0];
            float wa[4] = {wv.x, wv.y, wv.z, wv.w};
            float pa[4] = {pv.x, pv.y, pv.z, pv.w};
            #pragma unroll
            for (int i = 0; i < 4; ++i)
                #pragma unroll
                for (int j = 0; j < 4; ++j)
                    acc[i][j] += wa[i] * pa[j];
        }
        __syncthreads();
    }
    #pragma unroll
    for (int i = 0; i < 4; ++i) {
        int m = m0 + ml0 + i;
        float scale = gam[m] * rsqrtf(var[m] + 1e-5f);
        float base = b1[m] - mu[m];
        float bb = bet[m];
        #pragma unroll
        for (int j = 0; j < 4; ++j) {
            float y = (acc[i][j] + base) * scale + bb;
            float hs = y * fminf(fmaxf(y + 3.f, 0.f), 6.f) * (1.f / 6.f);
            a[(size_t)b * NCM * NL + (size_t)m * NL + ll0 + j] = hs;
        }
    }
}

// ---------------- Kernel 3: gh/gw = sigmoid(w @ a + b) ----------------
// grid: (NB, 2 sides, 4 o-tiles); block 256; thread 4o x 4h
__global__ __launch_bounds__(256) void k_gate(const float* __restrict__ a,
                                              const float* __restrict__ w2,
                                              const float* __restrict__ b2,
                                              const float* __restrict__ w3,
                                              const float* __restrict__ b3,
                                              float* __restrict__ gh,
                                              float* __restrict__ gw) {
    int b = blockIdx.x, side = blockIdx.y, ot = blockIdx.z;
    const float* wsel = side ? w3 : w2;
    const float* bsel = side ? b3 : b2;
    float* gsel = side ? gw : gh;
    int t = threadIdx.x;
    __shared__ float wt[32][64];   // [k][o]
    __shared__ float at[32][64];   // [k][h]
    int o0 = (t & 15) * 4, h0 = (t >> 4) * 4;
    float acc[4][4] = {};
    const float* ab = a + (size_t)b * NCM * NL + side * 64;

    for (int kc = 0; kc < NCM; kc += 32) {
        {   // stage w transposed: oi = t%64, kq = t/64 -> 8 k each (2 f4)
            int oi = t & 63, kq = t >> 6;
            #pragma unroll
            for (int i = 0; i < 2; ++i) {
                int k0 = kq * 8 + i * 4;
                float4 wv = *(const float4*)(wsel + (size_t)(ot * 64 + oi) * NCM + kc + k0);
                wt[k0 + 0][oi] = wv.x; wt[k0 + 1][oi] = wv.y;
                wt[k0 + 2][oi] = wv.z; wt[k0 + 3][oi] = wv.w;
            }
        }
        #pragma unroll
        for (int i = 0; i < 2; ++i) {        // stage a tile 32x64
            int f = t + i * 256;
            int ki = f >> 4, h4 = f & 15;
            *(float4*)&at[ki][h4 * 4] =
                *(const float4*)(ab + (size_t)(kc + ki) * NL + h4 * 4);
        }
        __syncthreads();
        #pragma unroll
        for (int kj = 0; kj < 32; ++kj) {
            float4 wv = *(const float4*)&wt[kj][o0];
            float4 av = *(const float4*)&at[kj][h0];
            float wa[4] = {wv.x, wv.y, wv.z, wv.w};
            float aa[4] = {av.x, av.y, av.z, av.w};
            #pragma unroll
            for (int i = 0; i < 4; ++i)
                #pragma unroll
                for (int j = 0; j < 4; ++j)
                    acc[i][j] += wa[i] * aa[j];
        }
        __syncthreads();
    }
    #pragma unroll
    for (int i = 0; i < 4; ++i) {
        int o = ot * 64 + o0 + i;
        float bias = bsel[o];
        #pragma unroll
        for (int j = 0; j < 4; ++j) {
            float v = acc[i][j] + bias;
            float g = 1.f / (1.f + __expf(-v));
            gsel[((size_t)b * NCO + o) * 64 + h0 + j] = g;
        }
    }
}

// ---------------- Kernel 4: out = x * gh[h] * gw[w] ----------------
__global__ __launch_bounds__(256) void k_apply(const float* __restrict__ x,
                                               const float* __restrict__ gh,
                                               const float* __restrict__ gw,
                                               float* __restrict__ out) {
    int plane = blockIdx.x;              // b*NC + c (o == c since Co==C)
    int t = threadIdx.x;
    const float4* px = (const float4*)(x + (size_t)plane * 4096);
    float4* po = (float4*)(out + (size_t)plane * 4096);
    const float* ghp = gh + (size_t)plane * 64;
    const float4* gwp = (const float4*)(gw + (size_t)plane * 64);
    #pragma unroll
    for (int i = 0; i < 4; ++i) {
        int f = t + i * 256;
        int row = f >> 4, w4 = f & 15;
        float4 v = px[f];
        float g = ghp[row];
        float4 gv = gwp[w4];
        v.x *= g * gv.x; v.y *= g * gv.y;
        v.z *= g * gv.z; v.w *= g * gv.w;
        po[f] = v;
    }
}

extern "C" void kernel_launch(void* const* d_in, const int* in_sizes, int n_in,
                              void* d_out, int out_size, void* d_ws, size_t ws_size,
                              hipStream_t stream) {
    const float* x   = (const float*)d_in[0];
    const float* w1  = (const float*)d_in[1];
    const float* b1  = (const float*)d_in[2];
    const float* gam = (const float*)d_in[3];
    const float* bet = (const float*)d_in[4];
    const float* mu  = (const float*)d_in[5];
    const float* var = (const float*)d_in[6];
    const float* w2  = (const float*)d_in[7];
    const float* b2  = (const float*)d_in[8];
    const float* w3  = (const float*)d_in[9];
    const float* b3  = (const float*)d_in[10];
    float* ws   = (float*)d_ws;
    float* pool = ws;                       // 32*256*128   = 1,048,576 f
    float* a    = ws + 1048576;             // 32*128*128   =   524,288 f
    float* gh   = ws + 1572864;             // 32*256*64    =   524,288 f
    float* gw   = ws + 2097152;             // 32*256*64    =   524,288 f
    float* out  = (float*)d_out;

    k_pool<<<NB * NC, 256, 0, stream>>>(x, pool);
    k_mlp1<<<dim3(NB, 4), 256, 0, stream>>>(pool, w1, b1, gam, bet, mu, var, a);
    k_gate<<<dim3(NB, 2, 4), 256, 0, stream>>>(a, w2, b2, w3, b3, gh, gw);
    k_apply<<<NB * NC, 256, 0, stream>>>(x, gh, gw, out);
}

// Round 3
// 85.193 us; speedup vs baseline: 1.0434x; 1.0434x over previous
//
#include <hip/hip_runtime.h>

#define NB 32
#define NC 256
#define NH 64
#define NW 64
#define NCM 128
#define NCO 256
#define NL 128   // NH+NW

typedef float v4f __attribute__((ext_vector_type(4)));

// ---------------- Kernel 1: H/W mean pooling ----------------
// grid: NB*NC blocks (one per plane), block 256 threads.
// pool layout: [b][c][l], l<64 = mean over W (xh), l>=64 = mean over H (xw)
__global__ __launch_bounds__(256) void k_pool(const float* __restrict__ x,
                                              float* __restrict__ pool) {
    int plane = blockIdx.x;                  // b*NC + c
    const float4* px = (const float4*)(x + (size_t)plane * 4096);
    int t = threadIdx.x;
    __shared__ float smem[256 * 4];

    float4 csum = make_float4(0.f, 0.f, 0.f, 0.f);
    for (int i = 0; i < 4; ++i) {
        int f = t + i * 256;                 // float4 index in plane (1024 total)
        float4 v = px[f];
        csum.x += v.x; csum.y += v.y; csum.z += v.z; csum.w += v.w;
        // row sum: row = f/16 = t/16 + 16*i, col4 = t%16 ; reduce 16-lane group
        float s = v.x + v.y + v.z + v.w;
        s += __shfl_xor(s, 1);
        s += __shfl_xor(s, 2);
        s += __shfl_xor(s, 4);
        s += __shfl_xor(s, 8);
        if ((t & 15) == 0) {
            int row = (t >> 4) + 16 * i;
            pool[(size_t)plane * NL + row] = s * 0.015625f;   // xh
        }
    }
    // csum holds cols [4*(t%16) .. +3] summed over rows {t/16 + 16*i}
    ((float4*)smem)[t] = csum;
    __syncthreads();
    if (t < 64) {
        int m = t >> 2, k = t & 3;           // column = 4m+k = t
        float acc = 0.f;
        #pragma unroll
        for (int g = 0; g < 16; ++g)
            acc += smem[(m + 16 * g) * 4 + k];
        pool[(size_t)plane * NL + 64 + t] = acc * 0.015625f;  // xw
    }
}

// ---------------- Kernel 2: y = w1 @ pool, BN, hswish ----------------
// grid: (NB, 8) — 16m-tile each; block 256 threads; thread: 2m x 4l
__global__ __launch_bounds__(256) void k_mlp1(const float* __restrict__ pool,
                                              const float* __restrict__ w1,
                                              const float* __restrict__ b1,
                                              const float* __restrict__ gam,
                                              const float* __restrict__ bet,
                                              const float* __restrict__ mu,
                                              const float* __restrict__ var,
                                              float* __restrict__ a) {
    int b = blockIdx.x, m0 = blockIdx.y * 16;
    int t = threadIdx.x;
    __shared__ float w1t[32][16];   // [c][m]
    __shared__ float pt[32][NL];    // [c][l]
    const float* poolb = pool + (size_t)b * NC * NL;
    int tm = t & 7;                 // 8 m-groups of 2
    int tl = t >> 3;                // 32 l-groups of 4
    float acc[2][4] = {};

    for (int cc = 0; cc < NC; cc += 32) {
        {   // stage w1 transposed: mi = t%16 (m), c0 = (t/16)*2
            int mi = t & 15, c0 = (t >> 4) * 2;
            float2 wv = *(const float2*)(w1 + (size_t)(m0 + mi) * NC + cc + c0);
            w1t[c0 + 0][mi] = wv.x; w1t[c0 + 1][mi] = wv.y;
        }
        #pragma unroll
        for (int i = 0; i < 4; ++i) {        // stage pool tile 32x128
            int f = t + i * 256;
            int ci = f >> 5, l4 = f & 31;
            *(float4*)&pt[ci][l4 * 4] =
                *(const float4*)(poolb + (size_t)(cc + ci) * NL + l4 * 4);
        }
        __syncthreads();
        #pragma unroll
        for (int cj = 0; cj < 32; ++cj) {
            float2 wv = *(const float2*)&w1t[cj][tm * 2];
            float4 pv = *(const float4*)&pt[cj][tl * 4];
            float wa[2] = {wv.x, wv.y};
            float pa[4] = {pv.x, pv.y, pv.z, pv.w};
            #pragma unroll
            for (int i = 0; i < 2; ++i)
                #pragma unroll
                for (int j = 0; j < 4; ++j)
                    acc[i][j] += wa[i] * pa[j];
        }
        __syncthreads();
    }
    #pragma unroll
    for (int i = 0; i < 2; ++i) {
        int m = m0 + tm * 2 + i;
        float scale = gam[m] * rsqrtf(var[m] + 1e-5f);
        float base = b1[m] - mu[m];
        float bb = bet[m];
        #pragma unroll
        for (int j = 0; j < 4; ++j) {
            float y = (acc[i][j] + base) * scale + bb;
            float hs = y * fminf(fmaxf(y + 3.f, 0.f), 6.f) * (1.f / 6.f);
            a[(size_t)b * NCM * NL + (size_t)m * NL + tl * 4 + j] = hs;
        }
    }
}

// ---------------- Kernel 3: gh/gw = sigmoid(w @ a + b) ----------------
// grid: (NB, 2 sides, 8 o-tiles); block 256; thread 2o x 4h
__global__ __launch_bounds__(256) void k_gate(const float* __restrict__ a,
                                              const float* __restrict__ w2,
                                              const float* __restrict__ b2,
                                              const float* __restrict__ w3,
                                              const float* __restrict__ b3,
                                              float* __restrict__ gh,
                                              float* __restrict__ gw) {
    int b = blockIdx.x, side = blockIdx.y, ot = blockIdx.z;
    const float* wsel = side ? w3 : w2;
    const float* bsel = side ? b3 : b2;
    float* gsel = side ? gw : gh;
    int t = threadIdx.x;
    __shared__ float wt[32][32];   // [k][o]
    __shared__ float at[32][64];   // [k][h]
    int to = t & 15;               // 16 o-groups of 2
    int th = t >> 4;               // 16 h-groups of 4
    float acc[2][4] = {};
    const float* ab = a + (size_t)b * NCM * NL + side * 64;

    for (int kc = 0; kc < NCM; kc += 32) {
        {   // stage w transposed: oi = t%32, k0 = (t/32)*4
            int oi = t & 31, k0 = (t >> 5) * 4;
            float4 wv = *(const float4*)(wsel + (size_t)(ot * 32 + oi) * NCM + kc + k0);
            wt[k0 + 0][oi] = wv.x; wt[k0 + 1][oi] = wv.y;
            wt[k0 + 2][oi] = wv.z; wt[k0 + 3][oi] = wv.w;
        }
        #pragma unroll
        for (int i = 0; i < 2; ++i) {        // stage a tile 32x64
            int f = t + i * 256;
            int ki = f >> 4, h4 = f & 15;
            *(float4*)&at[ki][h4 * 4] =
                *(const float4*)(ab + (size_t)(kc + ki) * NL + h4 * 4);
        }
        __syncthreads();
        #pragma unroll
        for (int kj = 0; kj < 32; ++kj) {
            float2 wv = *(const float2*)&wt[kj][to * 2];
            float4 av = *(const float4*)&at[kj][th * 4];
            float wa[2] = {wv.x, wv.y};
            float aa[4] = {av.x, av.y, av.z, av.w};
            #pragma unroll
            for (int i = 0; i < 2; ++i)
                #pragma unroll
                for (int j = 0; j < 4; ++j)
                    acc[i][j] += wa[i] * aa[j];
        }
        __syncthreads();
    }
    #pragma unroll
    for (int i = 0; i < 2; ++i) {
        int o = ot * 32 + to * 2 + i;
        float bias = bsel[o];
        #pragma unroll
        for (int j = 0; j < 4; ++j) {
            float v = acc[i][j] + bias;
            float g = 1.f / (1.f + __expf(-v));
            gsel[((size_t)b * NCO + o) * 64 + th * 4 + j] = g;
        }
    }
}

// ---------------- Kernel 4: out = x * gh[h] * gw[w] ----------------
// Non-temporal stores: out is never re-read; keep x resident in L3 so this
// kernel's x-read is an Infinity-Cache hit (x was just streamed by k_pool).
__global__ __launch_bounds__(256) void k_apply(const float* __restrict__ x,
                                               const float* __restrict__ gh,
                                               const float* __restrict__ gw,
                                               float* __restrict__ out) {
    int plane = blockIdx.x;              // b*NC + c (o == c since Co==C)
    int t = threadIdx.x;
    const float4* px = (const float4*)(x + (size_t)plane * 4096);
    v4f* po = (v4f*)(out + (size_t)plane * 4096);
    const float* ghp = gh + (size_t)plane * 64;
    const float4* gwp = (const float4*)(gw + (size_t)plane * 64);
    #pragma unroll
    for (int i = 0; i < 4; ++i) {
        int f = t + i * 256;
        int row = f >> 4, w4 = f & 15;
        float4 v = px[f];
        float g = ghp[row];
        float4 gv = gwp[w4];
        v4f r;
        r.x = v.x * g * gv.x; r.y = v.y * g * gv.y;
        r.z = v.z * g * gv.z; r.w = v.w * g * gv.w;
        __builtin_nontemporal_store(r, po + f);
    }
}

extern "C" void kernel_launch(void* const* d_in, const int* in_sizes, int n_in,
                              void* d_out, int out_size, void* d_ws, size_t ws_size,
                              hipStream_t stream) {
    const float* x   = (const float*)d_in[0];
    const float* w1  = (const float*)d_in[1];
    const float* b1  = (const float*)d_in[2];
    const float* gam = (const float*)d_in[3];
    const float* bet = (const float*)d_in[4];
    const float* mu  = (const float*)d_in[5];
    const float* var = (const float*)d_in[6];
    const float* w2  = (const float*)d_in[7];
    const float* b2  = (const float*)d_in[8];
    const float* w3  = (const float*)d_in[9];
    const float* b3  = (const float*)d_in[10];
    float* ws   = (float*)d_ws;
    float* pool = ws;                       // 32*256*128   = 1,048,576 f
    float* a    = ws + 1048576;             // 32*128*128   =   524,288 f
    float* gh   = ws + 1572864;             // 32*256*64    =   524,288 f
    float* gw   = ws + 2097152;             // 32*256*64    =   524,288 f
    float* out  = (float*)d_out;

    k_pool<<<NB * NC, 256, 0, stream>>>(x, pool);
    k_mlp1<<<dim3(NB, 8), 256, 0, stream>>>(pool, w1, b1, gam, bet, mu, var, a);
    k_gate<<<dim3(NB, 2, 8), 256, 0, stream>>>(a, w2, b2, w3, b3, gh, gw);
    k_apply<<<NB * NC, 256, 0, stream>>>(x, gh, gw, out);
}